// Round 1
// baseline (180.805 us; speedup 1.0000x reference)
//
#include <hip/hip_runtime.h>

#define KSIZE 29
#define PAD   14
#define TILE  64
#define HALO  (TILE + 2 * PAD)   // 92
#define IMG   256

__global__ __launch_bounds__(256) void gauss_sep_kernel(const float* __restrict__ x,
                                                        float* __restrict__ out) {
    __shared__ float s_in[HALO][HALO];   // 92*92*4 = 33856 B
    __shared__ float s_tmp[HALO][TILE];  // 92*64*4 = 23552 B

    const int tid = threadIdx.x;
    const int img = blockIdx.z;
    const int ty0 = blockIdx.y * TILE;
    const int tx0 = blockIdx.x * TILE;

    const float* __restrict__ src = x   + (size_t)img * IMG * IMG;
    float* __restrict__ dst       = out + (size_t)img * IMG * IMG;

    // Per-thread 1-D Gaussian weights (separable: k2d = g ⊗ g, both sum-1).
    float wr[KSIZE];
    {
        float sum = 0.f;
        #pragma unroll
        for (int i = 0; i < KSIZE; ++i) {
            float d = (float)(i - PAD);
            wr[i] = __expf(-d * d * (1.0f / (2.0f * 7.0f * 7.0f)));
            sum += wr[i];
        }
        float inv = 1.0f / sum;
        #pragma unroll
        for (int i = 0; i < KSIZE; ++i) wr[i] *= inv;
    }

    // ---- Phase 1: global -> LDS with reflect padding ----
    for (int idx = tid; idx < HALO * HALO; idx += 256) {
        int r = idx / HALO;
        int c = idx - r * HALO;
        int gy = ty0 + r - PAD;
        gy = gy < 0 ? -gy : (gy > IMG - 1 ? 2 * (IMG - 1) - gy : gy);
        int gx = tx0 + c - PAD;
        gx = gx < 0 ? -gx : (gx > IMG - 1 ? 2 * (IMG - 1) - gx : gx);
        s_in[r][c] = src[gy * IMG + gx];
    }
    __syncthreads();

    // ---- Phase 2: horizontal 1-D conv, 4 outputs/thread ----
    // items: 92 rows * 16 quad-columns = 1472
    for (int it = tid; it < HALO * (TILE / 4); it += 256) {
        int r  = it >> 4;
        int c0 = (it & 15) * 4;
        float v[32];
        #pragma unroll
        for (int m = 0; m < 8; ++m) {
            float4 t = *(const float4*)&s_in[r][c0 + 4 * m];
            v[4 * m + 0] = t.x; v[4 * m + 1] = t.y;
            v[4 * m + 2] = t.z; v[4 * m + 3] = t.w;
        }
        float a0 = 0.f, a1 = 0.f, a2 = 0.f, a3 = 0.f;
        #pragma unroll
        for (int k = 0; k < KSIZE; ++k) {
            a0 += wr[k] * v[k + 0];
            a1 += wr[k] * v[k + 1];
            a2 += wr[k] * v[k + 2];
            a3 += wr[k] * v[k + 3];
        }
        *(float4*)&s_tmp[r][c0] = make_float4(a0, a1, a2, a3);
    }
    __syncthreads();

    // ---- Phase 3: vertical 1-D conv, sliding window, 16 outputs/thread ----
    {
        const int c  = tid & 63;
        const int r0 = (tid >> 6) * 16;   // 4 waves cover rows 0..63
        float acc[16];
        #pragma unroll
        for (int j = 0; j < 16; ++j) acc[j] = 0.f;
        #pragma unroll
        for (int r = 0; r < 16 + KSIZE - 1; ++r) {   // 44 LDS reads for 16 outputs
            float v = s_tmp[r0 + r][c];
            #pragma unroll
            for (int j = 0; j < 16; ++j) {
                int k = r - j;
                if (k >= 0 && k < KSIZE) acc[j] += wr[k] * v;
            }
        }
        #pragma unroll
        for (int j = 0; j < 16; ++j) {
            dst[(size_t)(ty0 + r0 + j) * IMG + (tx0 + c)] = acc[j];
        }
    }
}

extern "C" void kernel_launch(void* const* d_in, const int* in_sizes, int n_in,
                              void* d_out, int out_size, void* d_ws, size_t ws_size,
                              hipStream_t stream) {
    const float* x = (const float*)d_in[0];
    float* out = (float*)d_out;
    const int images = in_sizes[0] / (IMG * IMG);   // 8*64 = 512
    dim3 grid(IMG / TILE, IMG / TILE, images);      // (4,4,512)
    gauss_sep_kernel<<<grid, dim3(256), 0, stream>>>(x, out);
}

// Round 2
// 97.904 us; speedup vs baseline: 1.8468x; 1.8468x over previous
//
#include <hip/hip_runtime.h>

#define IMG   256
#define TILE  64
#define KS    29
#define PAD   14
#define LDSS  100   // LDS row stride in floats: odd multiple of 4 (25*4) so that
                    // lane=row b128 column reads spread across all bank groups

// exp(-d^2/(2*49)) for d=0..14, hand-computed to ~1e-8; normalization folds at compile time.
static constexpr float GK[15] = {
    1.0f,        0.98984780f, 0.96000544f, 0.91225408f, 0.84936581f,
    0.77483743f, 0.69256933f, 0.60653066f, 0.52045012f, 0.43756474f,
    0.36044779f, 0.29092381f, 0.23006630f, 0.17826398f, 0.13533528f
};
static constexpr float GSUM =
    GK[0] + 2.0f * (GK[1] + GK[2] + GK[3] + GK[4] + GK[5] + GK[6] + GK[7] +
                    GK[8] + GK[9] + GK[10] + GK[11] + GK[12] + GK[13] + GK[14]);
static constexpr float WT[29] = {
    GK[14]/GSUM, GK[13]/GSUM, GK[12]/GSUM, GK[11]/GSUM, GK[10]/GSUM, GK[9]/GSUM, GK[8]/GSUM,
    GK[7]/GSUM,  GK[6]/GSUM,  GK[5]/GSUM,  GK[4]/GSUM,  GK[3]/GSUM,  GK[2]/GSUM, GK[1]/GSUM,
    GK[0]/GSUM,
    GK[1]/GSUM,  GK[2]/GSUM,  GK[3]/GSUM,  GK[4]/GSUM,  GK[5]/GSUM,  GK[6]/GSUM, GK[7]/GSUM,
    GK[8]/GSUM,  GK[9]/GSUM,  GK[10]/GSUM, GK[11]/GSUM, GK[12]/GSUM, GK[13]/GSUM, GK[14]/GSUM
};

__device__ __forceinline__ int refl(int p) {
    int a = p < 0 ? -p : p;        // reflect at 0
    int b = 510 - a;               // reflect at 255 (2*(IMG-1) - a)
    return a < b ? a : b;
}

__global__ __launch_bounds__(384, 8)
void gauss_sep2(const float* __restrict__ x, float* __restrict__ out) {
    __shared__ alignas(16) float s_tmp[TILE * LDSS];   // 25,600 B

    const int t   = threadIdx.x;
    const int img = blockIdx.z;
    const int y0  = blockIdx.y * TILE;
    const int x0  = blockIdx.x * TILE;

    const float* __restrict__ src = x   + (size_t)img * (IMG * IMG);
    float* __restrict__ dst       = out + (size_t)img * (IMG * IMG);

    // ---- Phase A: vertical conv, global -> LDS (coalesced reads, sliding window) ----
    {
        const int yg = t / 96;         // 0..3 (16 output rows each)
        const int xp = t - yg * 96;    // 0..95; active if < 92 (64 cols + 2*14 halo)
        if (xp < 92) {
            const int gx   = refl(x0 + xp - PAD);
            const int brow = y0 + yg * 16 - PAD;
            float acc[16];
            #pragma unroll
            for (int j = 0; j < 16; ++j) acc[j] = 0.f;
            #pragma unroll
            for (int s = 0; s < 16 + KS - 1; ++s) {      // 44 coalesced loads
                const int rr  = refl(brow + s);
                const float v = src[rr * IMG + gx];
                #pragma unroll
                for (int j = 0; j < 16; ++j) {
                    const int k = s - j;
                    if (k >= 0 && k < KS) acc[j] += WT[k] * v;   // literal-weight fmac
                }
            }
            #pragma unroll
            for (int j = 0; j < 16; ++j)
                s_tmp[(yg * 16 + j) * LDSS + xp] = acc[j];       // stride-1 lanes: conflict-free
        }
    }
    __syncthreads();

    // ---- Phase B: horizontal conv, LDS -> global. lane = row, ds_read_b128 down
    //      odd-stride(100) rows: each 8-lane group covers all 8 bank groups. ----
    {
        const int y  = t & 63;
        const int cg = t >> 6;          // 0..5; active if < 4 (16 cols each)
        if (cg < 4) {
            const int c0 = cg * 16;
            float acc[16];
            #pragma unroll
            for (int c = 0; c < 16; ++c) acc[c] = 0.f;
            const float4* srow = (const float4*)&s_tmp[y * LDSS + c0];
            #pragma unroll
            for (int m = 0; m < 11; ++m) {               // 44 floats = 11 x b128
                const float4 v4 = srow[m];
                #pragma unroll
                for (int q = 0; q < 4; ++q) {
                    const int p = 4 * m + q;
                    const float v = q == 0 ? v4.x : q == 1 ? v4.y : q == 2 ? v4.z : v4.w;
                    #pragma unroll
                    for (int c = 0; c < 16; ++c) {
                        const int k = p - c;
                        if (k >= 0 && k < KS) acc[c] += WT[k] * v;
                    }
                }
            }
            float4* orow = (float4*)&dst[(size_t)(y0 + y) * IMG + x0 + c0];
            #pragma unroll
            for (int m = 0; m < 4; ++m)
                orow[m] = make_float4(acc[4*m+0], acc[4*m+1], acc[4*m+2], acc[4*m+3]);
        }
    }
}

extern "C" void kernel_launch(void* const* d_in, const int* in_sizes, int n_in,
                              void* d_out, int out_size, void* d_ws, size_t ws_size,
                              hipStream_t stream) {
    const float* x = (const float*)d_in[0];
    float* out = (float*)d_out;
    const int images = in_sizes[0] / (IMG * IMG);   // 8*64 = 512
    dim3 grid(IMG / TILE, IMG / TILE, images);      // (4,4,512)
    gauss_sep2<<<grid, dim3(384), 0, stream>>>(x, out);
}

// Round 3
// 80.938 us; speedup vs baseline: 2.2339x; 1.2096x over previous
//
#include <hip/hip_runtime.h>

#define IMG   256
#define TILEY 64
#define KS    29
#define PAD   14
#define LDSS  284   // 256 + 2*14 halo; 71 float4s/row (71 mod 8 == 7 -> conflict-free lane-per-row b128 reads)

// exp(-d^2/(2*49)) for d=0..14; normalization folds at compile time.
static constexpr float GK[15] = {
    1.0f,        0.98984780f, 0.96000544f, 0.91225408f, 0.84936581f,
    0.77483743f, 0.69256933f, 0.60653066f, 0.52045012f, 0.43756474f,
    0.36044779f, 0.29092381f, 0.23006630f, 0.17826398f, 0.13533528f
};
static constexpr float GSUM =
    GK[0] + 2.0f * (GK[1] + GK[2] + GK[3] + GK[4] + GK[5] + GK[6] + GK[7] +
                    GK[8] + GK[9] + GK[10] + GK[11] + GK[12] + GK[13] + GK[14]);
static constexpr float WT[29] = {
    GK[14]/GSUM, GK[13]/GSUM, GK[12]/GSUM, GK[11]/GSUM, GK[10]/GSUM, GK[9]/GSUM, GK[8]/GSUM,
    GK[7]/GSUM,  GK[6]/GSUM,  GK[5]/GSUM,  GK[4]/GSUM,  GK[3]/GSUM,  GK[2]/GSUM, GK[1]/GSUM,
    GK[0]/GSUM,
    GK[1]/GSUM,  GK[2]/GSUM,  GK[3]/GSUM,  GK[4]/GSUM,  GK[5]/GSUM,  GK[6]/GSUM, GK[7]/GSUM,
    GK[8]/GSUM,  GK[9]/GSUM,  GK[10]/GSUM, GK[11]/GSUM, GK[12]/GSUM, GK[13]/GSUM, GK[14]/GSUM
};

__device__ __forceinline__ int refl(int p) {
    int a = p < 0 ? -p : p;        // reflect at 0
    int b = 2 * (IMG - 1) - a;     // reflect at 255
    return a < b ? a : b;
}

__global__ __launch_bounds__(1024, 8)
void gauss_strip(const float* __restrict__ x, float* __restrict__ out) {
    __shared__ alignas(16) float s[TILEY * LDSS];   // 72,704 B -> 2 blocks/CU

    const int t   = threadIdx.x;
    const int img = blockIdx.y;
    const int y0  = blockIdx.x * TILEY;

    const float* __restrict__ src = x   + (size_t)img * (IMG * IMG);
    float*       __restrict__ dst = out + (size_t)img * (IMG * IMG);

    // ---- Phase A: vertical conv, global -> LDS. 1024 threads = 256 cols x 4 rowgroups.
    {
        const int col  = t & 255;
        const int rg   = t >> 8;           // 0..3, wave-uniform
        const int r0   = rg * 16;          // strip-local output rows r0..r0+15
        const int brow = y0 + r0 - PAD;    // first input row of the 44-row window

        float acc[16];
        #pragma unroll
        for (int j = 0; j < 16; ++j) acc[j] = 0.f;

        if (brow >= 0 && brow + 43 <= IMG - 1) {
            // interior (14 of 16 strip/rowgroup combos): pure pointer-walk loads
            const float* p = src + (size_t)brow * IMG + col;
            #pragma unroll
            for (int sidx = 0; sidx < 16 + KS - 1; ++sidx) {
                const float v = p[sidx * IMG];
                #pragma unroll
                for (int j = 0; j < 16; ++j) {
                    const int k = sidx - j;
                    if (k >= 0 && k < KS) acc[j] += WT[k] * v;   // literal-weight fmac
                }
            }
        } else {
            // boundary rowgroups: reflected row indices
            #pragma unroll
            for (int sidx = 0; sidx < 16 + KS - 1; ++sidx) {
                const float v = src[refl(brow + sidx) * IMG + col];
                #pragma unroll
                for (int j = 0; j < 16; ++j) {
                    const int k = sidx - j;
                    if (k >= 0 && k < KS) acc[j] += WT[k] * v;
                }
            }
        }

        // write tile + mirrored horizontal halo (reflect-101 within full-width row)
        const int pos = PAD + col;
        #pragma unroll
        for (int j = 0; j < 16; ++j)
            s[(r0 + j) * LDSS + pos] = acc[j];                 // stride-1 lanes: conflict-free
        if (col >= 1 && col <= PAD) {
            #pragma unroll
            for (int j = 0; j < 16; ++j)
                s[(r0 + j) * LDSS + (PAD - col)] = acc[j];     // left halo
        } else if (col >= IMG - 1 - PAD && col <= IMG - 2) {
            #pragma unroll
            for (int j = 0; j < 16; ++j)
                s[(r0 + j) * LDSS + (2 * (IMG - 1) + PAD - col)] = acc[j];  // right halo
        }
    }
    __syncthreads();

    // ---- Phase B: horizontal conv, LDS -> global. 1024 threads = 64 rows x 16 colgroups.
    {
        const int row = t & 63;           // lane = row -> b128 column reads hit all 8 bank groups
        const int cg  = t >> 6;           // 0..15
        const int c0  = cg * 16;

        float acc[16];
        #pragma unroll
        for (int c = 0; c < 16; ++c) acc[c] = 0.f;

        const float4* srow = (const float4*)&s[row * LDSS + c0];   // pos c0 == col c0-14
        #pragma unroll
        for (int m = 0; m < 11; ++m) {    // 44 floats = 11 x b128
            const float4 v4 = srow[m];
            #pragma unroll
            for (int q = 0; q < 4; ++q) {
                const int p = 4 * m + q;
                const float v = q == 0 ? v4.x : q == 1 ? v4.y : q == 2 ? v4.z : v4.w;
                #pragma unroll
                for (int c = 0; c < 16; ++c) {
                    const int k = p - c;
                    if (k >= 0 && k < KS) acc[c] += WT[k] * v;
                }
            }
        }

        float4* orow = (float4*)&dst[(size_t)(y0 + row) * IMG + c0];
        #pragma unroll
        for (int m = 0; m < 4; ++m)
            orow[m] = make_float4(acc[4*m+0], acc[4*m+1], acc[4*m+2], acc[4*m+3]);
    }
}

extern "C" void kernel_launch(void* const* d_in, const int* in_sizes, int n_in,
                              void* d_out, int out_size, void* d_ws, size_t ws_size,
                              hipStream_t stream) {
    const float* x = (const float*)d_in[0];
    float* out = (float*)d_out;
    const int images = in_sizes[0] / (IMG * IMG);   // 8*64 = 512
    dim3 grid(IMG / TILEY, images);                 // (4, 512)
    gauss_strip<<<grid, dim3(1024), 0, stream>>>(x, out);
}